// Round 4
// baseline (353.362 us; speedup 1.0000x reference)
//
#include <hip/hip_runtime.h>

// VQ-VAE EMA vector quantizer, fp32 in/out.
// N=65536 rows (32*2048), D=256, K=1024 codes.
//
// R8:  distance GEMM on matrix cores via double-f16 split (3 mfma per K32):
//      128*z = zh+zl, 128*e = eh+el; acc = zh*eh + zh*el + zl*eh (fp32 acc).
//      Exact power-of-2 descale: d = fmaf(acc,-0x1p-13f,zsq)+esq.
// R9:  flat K'=768, tri-buffer, counted vmcnt. 142 us.
// R10: B fragment-major direct-to-reg (L2), A-only LDS. 157 us.
//      FETCH 447->111 MB but NOT faster: R8/R9/R10 all ~30% MfmaUtil --
//      dur == hbm_bytes/achieved_BW with achieved BW collapsing (1.15 TB/s)
//      => memory-CONCURRENCY bound (2 waves/SIMD, ~9 vmem in flight/wave).
// R11: raise request concurrency, not BW:
//      - K-step 64: 24 iters, half the barriers; 2 gl_lds/thread/iter;
//        A tri-buffer staged 2 iters ahead; B prefetched half-iter ahead;
//        counted s_waitcnt vmcnt(18) per barrier (18 = 8+8+2 vmem newer
//        than Astage(it+1); in-order vmcnt retirement).
//      - epilogue split into vq_epi (1024 blk x 256 thr, tiny regs, high
//        occupancy): streams the 128 MB z/zq phase at full HBM concurrency
//        instead of trailing a 2-wave/SIMD GEMM block. Main kernel now
//        touches only zhl + codes.

#define DDIM 256
#define DQ   64
#define KC   1024
#define NROW 65536
#define BM   128     // fp32-fallback tile
#define BN   128
#define BD   32
#define LS   34
#define DECAYF 0.99f
#define OMDF   0.01f
#define BETAF  0.25f
#define EPSF   1e-5f

// R11 mfma geometry
#define BMR  128     // rows per block
#define NIT  24      // 2 passes x 12 K-steps of 64

typedef _Float16 f16;
typedef _Float16 f16x8 __attribute__((ext_vector_type(8)));
typedef float    f32x4 __attribute__((ext_vector_type(4)));

__device__ __forceinline__ void gl_lds16(const f16* g, f16* l) {
    __builtin_amdgcn_global_load_lds(
        (const __attribute__((address_space(1))) void*)g,
        (__attribute__((address_space(3))) void*)l, 16, 0, 0);
}

// one-shot ||e||^2 (fallback path only)
__global__ __launch_bounds__(256) void vq_esq(const float* __restrict__ emb,
                                              float* __restrict__ esq_g)
{
    int k = blockIdx.x * 256 + threadIdx.x;
    const float4* ep = (const float4*)(emb + (size_t)k * DDIM);
    float s = 0.f;
    for (int q = 0; q < DQ; ++q) {
        float4 v = ep[q];
        s += v.x * v.x + v.y * v.y + v.z * v.z + v.w * v.w;
    }
    esq_g[k] = s;
}

// f32 -> double-f16 split, plane layout [row][zh(256) | zl(256)] f16.
// Also emits ||x||^2 per row.
__global__ __launch_bounds__(256) void vq_prep(const float* __restrict__ src,
                                               f16* __restrict__ dst,
                                               float* __restrict__ sq_g)
{
    int t   = blockIdx.x * 256 + threadIdx.x;
    int row = t >> 5;
    int c   = t & 31;
    const float4* sp = (const float4*)(src + (size_t)row * DDIM + c * 8);
    float4 v0 = sp[0], v1 = sp[1];
    float x[8] = {v0.x, v0.y, v0.z, v0.w, v1.x, v1.y, v1.z, v1.w};
    f16x8 h, l;
    float s = 0.f;
#pragma unroll
    for (int j = 0; j < 8; ++j) {
        float xs = x[j] * 128.0f;
        f16 hh = (f16)xs;
        h[j] = hh;
        l[j] = (f16)(xs - (float)hh);
        s += x[j] * x[j];
    }
    f16* rp = dst + (size_t)row * 512;
    *(f16x8*)(rp + c * 8)       = h;
    *(f16x8*)(rp + 256 + c * 8) = l;
    s += __shfl_xor(s, 1);
    s += __shfl_xor(s, 2);
    s += __shfl_xor(s, 4);
    s += __shfl_xor(s, 8);
    s += __shfl_xor(s, 16);
    if (c == 0) sq_g[row] = s;
}

// Codebook -> fragment-major f16 split (same layout as R10, proven).
// ehl2[plane(2)][kb(8)][cg(64)][lane(64)][8 f16]: wave B-frag load for
// (plane,kb,cg) = base + lane*16B, one coalesced 1KB read.
__global__ __launch_bounds__(256) void vq_prep_e(const float* __restrict__ emb,
                                                 f16* __restrict__ ehl2,
                                                 float* __restrict__ esq_g)
{
    int t     = blockIdx.x * 256 + threadIdx.x;
    int c     = t >> 5;          // code
    int chunk = t & 31;          // k0 = chunk*8
    const float4* sp = (const float4*)(emb + (size_t)c * DDIM + chunk * 8);
    float4 v0 = sp[0], v1 = sp[1];
    float x[8] = {v0.x, v0.y, v0.z, v0.w, v1.x, v1.y, v1.z, v1.w};
    f16x8 h, l;
    float s = 0.f;
#pragma unroll
    for (int j = 0; j < 8; ++j) {
        float xs = x[j] * 128.0f;
        f16 hh = (f16)xs;
        h[j] = hh;
        l[j] = (f16)(xs - (float)hh);
        s += x[j] * x[j];
    }
    int kb = chunk >> 2, kg = chunk & 3;
    int cg = c >> 4;
    int lanep = kg * 16 + (c & 15);
    size_t idx = ((size_t)(kb * 64 + cg)) * 512 + lanep * 8;
    *(f16x8*)(ehl2 + idx)          = h;          // plane 0 (eh)
    *(f16x8*)(ehl2 + 262144 + idx) = l;          // plane 1 (el)
    s += __shfl_xor(s, 1);
    s += __shfl_xor(s, 2);
    s += __shfl_xor(s, 4);
    s += __shfl_xor(s, 8);
    s += __shfl_xor(s, 16);
    if (chunk == 0) esq_g[c] = s;
}

// ---- R11 main kernel ----
// 512 blocks x 512 thr (8 waves: wr=wave>>2 in {0,1}, wc=wave&3).
// Wave tile 64 rows x 128 cols; acc[4][8] f32x4.
// it = 0..23: pass = it/12 (cols pass*512..), s = it%12 over flat K'=768
//   (s 0-3: zh*eh, 4-7: zh*el, 8-11: zl*eh), 64 K per iter (ks=0,1).

#define ASTAGE(b_, s_) do {                                                 \
    int off_ = (((s_) >= 8) ? 256 : 0) + ((s_) & 3) * 64;                   \
    gl_lds16(asrc0 + off_, &Abuf[b_][0] + tid * 8);                         \
    gl_lds16(asrc1 + off_, &Abuf[b_][0] + (tid + 512) * 8);                 \
} while (0)

#define BLOAD(dst_, it_, ks_) do {                                          \
    int itc_ = (it_) > NIT - 1 ? NIT - 1 : (it_);                           \
    int ps_ = itc_ / 12, sb_ = itc_ % 12;                                   \
    int pl_ = (sb_ >= 4 && sb_ < 8) ? 1 : 0;                                \
    int kb_ = (sb_ & 3) * 2 + (ks_);                                        \
    const f16* bp_ = ehl2 + (((pl_ * 8 + kb_) * 64 + ps_ * 32 + wc * 8) << 9) \
                   + lane * 8;                                              \
    _Pragma("unroll")                                                       \
    for (int j_ = 0; j_ < 8; ++j_) dst_[j_] = *(const f16x8*)(bp_ + j_ * 512); \
} while (0)

#define MM(bank_, Ab_, ks_) do {                                            \
    f16x8 a0_ = *(const f16x8*)((Ab_) + aoff[0][ks_]);                      \
    f16x8 a1_ = *(const f16x8*)((Ab_) + aoff[1][ks_]);                      \
    f16x8 a2_ = *(const f16x8*)((Ab_) + aoff[2][ks_]);                      \
    f16x8 a3_ = *(const f16x8*)((Ab_) + aoff[3][ks_]);                      \
    __builtin_amdgcn_s_setprio(1);                                          \
    _Pragma("unroll")                                                       \
    for (int j_ = 0; j_ < 8; ++j_) {                                        \
        acc[0][j_] = __builtin_amdgcn_mfma_f32_16x16x32_f16(a0_, bank_[j_], acc[0][j_], 0, 0, 0); \
        acc[1][j_] = __builtin_amdgcn_mfma_f32_16x16x32_f16(a1_, bank_[j_], acc[1][j_], 0, 0, 0); \
        acc[2][j_] = __builtin_amdgcn_mfma_f32_16x16x32_f16(a2_, bank_[j_], acc[2][j_], 0, 0, 0); \
        acc[3][j_] = __builtin_amdgcn_mfma_f32_16x16x32_f16(a3_, bank_[j_], acc[3][j_], 0, 0, 0); \
    }                                                                       \
    __builtin_amdgcn_s_setprio(0);                                          \
} while (0)

#define FOLD(P) do {                                                        \
    _Pragma("unroll")                                                       \
    for (int i_ = 0; i_ < 4; ++i_) {                                        \
      _Pragma("unroll")                                                     \
      for (int t_ = 0; t_ < 4; ++t_) {                                      \
        int row_ = wr * 64 + i_ * 16 + kg * 4 + t_;                         \
        float zq2_ = zsq_s[row_];                                           \
        float bv_ = 3.4e38f; int bix_ = 0;                                  \
        _Pragma("unroll")                                                   \
        for (int j_ = 0; j_ < 8; ++j_) {                                    \
          int col_ = (P) * 512 + wc * 128 + j_ * 16 + c16;                  \
          float d_ = fmaf(acc[i_][j_][t_], -0x1p-13f, zq2_) + esq_s[col_];  \
          if (d_ < bv_) { bv_ = d_; bix_ = col_; }                          \
        }                                                                   \
        _Pragma("unroll")                                                   \
        for (int m_ = 1; m_ < 16; m_ <<= 1) {                               \
          float ov_ = __shfl_xor(bv_, m_);                                  \
          int   oi_ = __shfl_xor(bix_, m_);                                 \
          if (ov_ < bv_ || (ov_ == bv_ && oi_ < bix_)) { bv_ = ov_; bix_ = oi_; } \
        }                                                                   \
        if (c16 == 0) {                                                     \
          red_v[row_ * 9 + (P) * 4 + wc] = bv_;                             \
          red_i[row_ * 9 + (P) * 4 + wc] = bix_;                            \
        }                                                                   \
      }                                                                     \
    }                                                                       \
    _Pragma("unroll")                                                       \
    for (int i_ = 0; i_ < 4; ++i_)                                          \
      _Pragma("unroll")                                                     \
      for (int j_ = 0; j_ < 8; ++j_) acc[i_][j_] = zero4;                   \
} while (0)

__global__ __launch_bounds__(512) void vq_main_mfma(
    const f16*  __restrict__ zhl,        // [N][zh 256 | zl 256] f16
    const f16*  __restrict__ ehl2,       // fragment-major codebook (1 MB)
    const float* __restrict__ esq_g,     // [K]
    const float* __restrict__ zsq_g,     // [N]
    float* __restrict__ out_codes)
{
    __shared__ f16   Abuf[3][8192];      // 3 x 16 KB A tri-buffer
    __shared__ float esq_s[KC];          // 4 KB
    __shared__ float zsq_s[BMR];         // 512 B
    __shared__ float red_v[BMR * 9];     // 4.5 KB (pad 9 vs 8)
    __shared__ int   red_i[BMR * 9];     // 4.5 KB  -> 62 KB total (static)

    const int tid  = threadIdx.x;
    const int row0 = blockIdx.x * BMR;
    const int wave = tid >> 6, lane = tid & 63;
    const int wr   = wave >> 2, wc = wave & 3;   // 2M x 4N wave grid
    const int kg   = lane >> 4, c16 = lane & 15;

    // ---- prologue ----
    { float2 v = ((const float2*)esq_g)[tid];
      *(float2*)(esq_s + tid * 2) = v; }
    if (tid < BMR) zsq_s[tid] = zsq_g[row0 + tid];

    // A-stage: thread stages rows ar and ar+64, chunk ach, XOR-swizzled src,
    // linear LDS dest. (ar&7) == ((ar+64)&7) so one XOR serves both.
    const int ar = tid >> 3, ach = tid & 7;
    const f16* asrc0 = zhl + (size_t)(row0 + ar) * 512 + (ach ^ (ar & 7)) * 8;
    const f16* asrc1 = asrc0 + (size_t)64 * 512;

    // A-frag LDS offsets (f16 units), matching the staging swizzle.
    int aoff[4][2];
#pragma unroll
    for (int i = 0; i < 4; ++i)
#pragma unroll
        for (int ks = 0; ks < 2; ++ks)
            aoff[i][ks] = (wr * 64 + i * 16 + c16) * 64
                        + (((ks * 4 + kg) ^ (c16 & 7)) * 8);

    f16x8 b0[8], b1[8];
    ASTAGE(0, 0);
    ASTAGE(1, 1);
    BLOAD(b0, 0, 0);
    asm volatile("s_waitcnt lgkmcnt(0)" ::: "memory");  // esq/zsq ds_writes
    asm volatile("s_waitcnt vmcnt(10)" ::: "memory");   // Astage(0) landed
    __builtin_amdgcn_s_barrier();

    f32x4 acc[4][8];
    const f32x4 zero4 = {0.f, 0.f, 0.f, 0.f};
#pragma unroll
    for (int i = 0; i < 4; ++i)
#pragma unroll
        for (int j = 0; j < 8; ++j) acc[i][j] = zero4;

#pragma unroll 1
    for (int it = 0; it < NIT; ++it) {
        const f16* Ab = &Abuf[it % 3][0];
        BLOAD(b1, it, 1);                 // B for ks1, half-iter ahead
        MM(b0, Ab, 0);
        BLOAD(b0, it + 1, 0);             // B for next iter ks0
        {                                 // A stage 2 iters ahead
            int its = it + 2;
            int bd  = its % 3;            // dest buffer: free since it-1
            int ssv = (its > NIT - 1 ? NIT - 1 : its) % 12;  // clamp src only
            ASTAGE(bd, ssv);
        }
        MM(b1, Ab, 1);
        if ((it % 12) == 11) { FOLD(it / 12); }
        // counted: Astage(it+1) retired (18 vmem issued after it, in-order),
        // prefetched B + Astage(it+2) stay in flight across the barrier.
        asm volatile("s_waitcnt vmcnt(18)" ::: "memory");
        __builtin_amdgcn_s_barrier();
    }

    // ---- final argmin scan: 8 candidates/row (pass-major = ascending col) --
    __syncthreads();
    if (tid < BMR) {
        float bv = red_v[tid * 9];
        int   bi = red_i[tid * 9];
#pragma unroll
        for (int t = 1; t < 8; ++t) {
            float v  = red_v[tid * 9 + t];
            int   ix = red_i[tid * 9 + t];
            if (v < bv || (v == bv && ix < bi)) { bv = v; bi = ix; }
        }
        out_codes[row0 + tid] = (float)bi;
    }
}

// ---- epilogue kernel: gather z_q (exact f32), write z_q_st, commit loss ----
// High occupancy (tiny regs, 256 thr) -> streams 128 MB at full concurrency.
__global__ __launch_bounds__(256) void vq_epi(
    const float* __restrict__ z,
    const float* __restrict__ emb,
    const float* __restrict__ codes_f,
    float* __restrict__ out_zq,
    float* __restrict__ loss_acc)
{
    __shared__ int   codes_s[64];
    __shared__ float lred[256];
    const int tid  = threadIdx.x;
    const int row0 = blockIdx.x * 64;
    const int wave = tid >> 6, lane = tid & 63;

    if (tid < 64) codes_s[tid] = (int)codes_f[row0 + tid];
    __syncthreads();

    float lp = 0.f;
#pragma unroll 1
    for (int r = wave; r < 64; r += 4) {
        int code = codes_s[r];
        float4 e4 = *(const float4*)(emb + (size_t)code * DDIM + lane * 4);
        float4 z4 = *(const float4*)(z + (size_t)(row0 + r) * DDIM + lane * 4);
        float dx = e4.x - z4.x, dy = e4.y - z4.y, dz = e4.z - z4.z, dw = e4.w - z4.w;
        float4 o;
        o.x = z4.x + dx; o.y = z4.y + dy; o.z = z4.z + dz; o.w = z4.w + dw;
        *(float4*)(out_zq + (size_t)(row0 + r) * DDIM + lane * 4) = o;
        lp += dx * dx + dy * dy + dz * dz + dw * dw;
    }
    lred[tid] = lp;
    __syncthreads();
    for (int s = 128; s > 0; s >>= 1) {
        if (tid < s) lred[tid] += lred[tid + s];
        __syncthreads();
    }
    if (tid == 0) atomicAdd(loss_acc, lred[0]);
}

// ---------- R7 fp32 kernel, kept verbatim as ws_size fallback ----------
__global__ __launch_bounds__(256) void vq_main_f32(
    const float* __restrict__ z,
    const float* __restrict__ emb,
    const float* __restrict__ esq_g,
    float* __restrict__ out_zq,
    float* __restrict__ out_codes,
    float* __restrict__ loss_acc)
{
    __shared__ float zs[BM * LS];
    __shared__ float es[BN * LS];
    __shared__ float esq_s[KC];
    __shared__ float zsq_s[BM];
    float* red_v   = zs;
    int*   red_i   = (int*)(zs + 2048);
    int*   codes_s = (int*)es;
    float* lred    = es + 128;

    const int tid  = threadIdx.x;
    const int row0 = blockIdx.x * BM;
    const int trow = tid >> 4;
    const int tcol = tid & 15;

    {
        const float4* eg = (const float4*)esq_g;
        float4 v = eg[tid];
        *(float4*)(esq_s + tid * 4) = v;
    }
    if (tid < BM) {
        const float4* zp = (const float4*)(z + (size_t)(row0 + tid) * DDIM);
        float s = 0.f;
        for (int q = 0; q < DQ; ++q) {
            float4 v = zp[q];
            s += v.x * v.x + v.y * v.y + v.z * v.z + v.w * v.w;
        }
        zsq_s[tid] = s;
    }

    const int r0 = tid >> 3;
    const int q0 = tid & 7;
    const float* zp0 = z + (size_t)(row0 + r0) * DDIM + q0 * 4;
    const float* ep0 = emb + (size_t)r0 * DDIM + q0 * 4;
    const int ls0 = r0 * LS + q0 * 4;

    float4 pz[4], pe[4];
#pragma unroll
    for (int it = 0; it < 4; ++it) {
        pz[it] = *(const float4*)(zp0 + it * 32 * DDIM);
        pe[it] = *(const float4*)(ep0 + it * 32 * DDIM);
    }

    float runv[8];
    int   runi[8];
#pragma unroll
    for (int i = 0; i < 8; ++i) { runv[i] = 3.4e38f; runi[i] = 0; }

#pragma unroll 1
    for (int kt = 0; kt < KC / BN; ++kt) {
        float acc[8][8];
#pragma unroll
        for (int i = 0; i < 8; ++i)
#pragma unroll
            for (int j = 0; j < 8; ++j) acc[i][j] = 0.f;

#pragma unroll 1
        for (int dc = 0; dc < DDIM / BD; ++dc) {
            __syncthreads();
#pragma unroll
            for (int it = 0; it < 4; ++it) {
                int o = ls0 + it * 32 * LS;
                *(float2*)(zs + o)     = make_float2(pz[it].x, pz[it].y);
                *(float2*)(zs + o + 2) = make_float2(pz[it].z, pz[it].w);
                *(float2*)(es + o)     = make_float2(pe[it].x, pe[it].y);
                *(float2*)(es + o + 2) = make_float2(pe[it].z, pe[it].w);
            }
            __syncthreads();
            {
                int ndc = dc + 1, nkt = kt;
                if (ndc == DDIM / BD) { ndc = 0; ++nkt; }
                if (nkt < KC / BN) {
                    size_t zo = (size_t)ndc * BD;
                    size_t eo = (size_t)nkt * BN * DDIM + (size_t)ndc * BD;
#pragma unroll
                    for (int it = 0; it < 4; ++it) {
                        pz[it] = *(const float4*)(zp0 + it * 32 * DDIM + zo);
                        pe[it] = *(const float4*)(ep0 + it * 32 * DDIM + eo);
                    }
                }
            }
#pragma unroll
            for (int s = 0; s < BD / 2; ++s) {
                float2 a2[8], b2[8];
#pragma unroll
                for (int i = 0; i < 8; ++i)
                    a2[i] = *(const float2*)(zs + (trow + 16 * i) * LS + s * 2);
#pragma unroll
                for (int j = 0; j < 8; ++j)
                    b2[j] = *(const float2*)(es + (tcol + 16 * j) * LS + s * 2);
#pragma unroll
                for (int i = 0; i < 8; ++i)
#pragma unroll
                    for (int j = 0; j < 8; ++j)
                        acc[i][j] = fmaf(a2[i].y, b2[j].y,
                                     fmaf(a2[i].x, b2[j].x, acc[i][j]));
            }
        }
#pragma unroll
        for (int i = 0; i < 8; ++i) {
            float zq2 = zsq_s[trow + 16 * i];
#pragma unroll
            for (int j = 0; j < 8; ++j) {
                int col = kt * BN + tcol + 16 * j;
                float dist = zq2 - 2.f * acc[i][j] + esq_s[col];
                if (dist < runv[i]) { runv[i] = dist; runi[i] = col; }
            }
        }
    }

    __syncthreads();
#pragma unroll
    for (int i = 0; i < 8; ++i) {
        int lr = trow + 16 * i;
        red_v[lr * 16 + tcol] = runv[i];
        red_i[lr * 16 + tcol] = runi[i];
    }
    __syncthreads();
    if (tid < BM) {
        float bv = red_v[tid * 16];
        int   bi = red_i[tid * 16];
        for (int t = 1; t < 16; ++t) {
            float v  = red_v[tid * 16 + t];
            int   ix = red_i[tid * 16 + t];
            if (v < bv || (v == bv && ix < bi)) { bv = v; bi = ix; }
        }
        codes_s[tid] = bi;
        out_codes[row0 + tid] = (float)bi;
    }
    __syncthreads();

    const int wavf = tid >> 6;
    const int lanf = tid & 63;
    float lp = 0.f;
    for (int r = wavf; r < BM; r += 4) {
        int code = codes_s[r];
        float4 e4 = *(const float4*)(emb + (size_t)code * DDIM + lanf * 4);
        float4 z4 = *(const float4*)(z + (size_t)(row0 + r) * DDIM + lanf * 4);
        float dx = e4.x - z4.x, dy = e4.y - z4.y, dz = e4.z - z4.z, dw = e4.w - z4.w;
        float4 o;
        o.x = z4.x + dx; o.y = z4.y + dy; o.z = z4.z + dz; o.w = z4.w + dw;
        *(float4*)(out_zq + (size_t)(row0 + r) * DDIM + lanf * 4) = o;
        lp += dx * dx + dy * dy + dz * dz + dw * dw;
    }
    lred[tid] = lp;
    __syncthreads();
    for (int s = 128; s > 0; s >>= 1) {
        if (tid < s) lred[tid] += lred[tid + s];
        __syncthreads();
    }
    if (tid == 0) atomicAdd(loss_acc, lred[0]);
}

// One block per code k; scan codes (L2-resident), gather rows coalesced.
__global__ __launch_bounds__(256) void vq_scatter(
    const float* __restrict__ z,
    const float* __restrict__ codes_f,
    float* __restrict__ embed_sum,
    float* __restrict__ counts)
{
    __shared__ int list[1024];
    __shared__ int nmatch;
    const int k   = blockIdx.x;
    const int tid = threadIdx.x;

    float acc = 0.f;
    int total = 0;
    if (tid == 0) nmatch = 0;
    __syncthreads();

    for (int base = 0; base < NROW; base += 1024) {
        float4 c4 = *(const float4*)(codes_f + base + tid * 4);
        int i0 = base + tid * 4;
        if ((int)c4.x == k) { int p = atomicAdd(&nmatch, 1); list[p] = i0; }
        if ((int)c4.y == k) { int p = atomicAdd(&nmatch, 1); list[p] = i0 + 1; }
        if ((int)c4.z == k) { int p = atomicAdd(&nmatch, 1); list[p] = i0 + 2; }
        if ((int)c4.w == k) { int p = atomicAdd(&nmatch, 1); list[p] = i0 + 3; }
        __syncthreads();
        int nm = nmatch;
        for (int i = 0; i < nm; ++i)
            acc += z[(size_t)list[i] * DDIM + tid];
        total += nm;
        __syncthreads();
        if (tid == 0) nmatch = 0;
        __syncthreads();
    }
    embed_sum[(size_t)k * DDIM + tid] = acc;
    if (tid == 0) counts[k] = (float)total;
}

__global__ void vq_finalize(const float* __restrict__ cluster_size,
                            const float* __restrict__ counts,
                            const float* __restrict__ loss_acc,
                            float* __restrict__ out_ncs,
                            float* __restrict__ out_loss,
                            float* __restrict__ cs_sm,
                            float inv_ND)
{
    __shared__ float sred[KC];
    const int tid = threadIdx.x;
    float ncs = cluster_size[tid] * DECAYF + counts[tid] * OMDF;
    out_ncs[tid] = ncs;
    sred[tid] = ncs;
    __syncthreads();
    for (int s = KC / 2; s > 0; s >>= 1) {
        if (tid < s) sred[tid] += sred[tid + s];
        __syncthreads();
    }
    float n = sred[0];
    cs_sm[tid] = (ncs + EPSF) / (n + (float)KC * EPSF) * n;
    if (tid == 0) out_loss[0] = BETAF * loss_acc[0] * inv_ND;
}

__global__ void vq_embed(const float* __restrict__ embed_avg,
                         const float* __restrict__ embed_sum,
                         const float* __restrict__ cs_sm,
                         float* __restrict__ out_nea,
                         float* __restrict__ out_nemb)
{
    int idx = blockIdx.x * blockDim.x + threadIdx.x;
    int k = idx >> 6;
    float4 ea = ((const float4*)embed_avg)[idx];
    float4 s4 = ((const float4*)embed_sum)[idx];
    float4 nea;
    nea.x = ea.x * DECAYF + s4.x * OMDF;
    nea.y = ea.y * DECAYF + s4.y * OMDF;
    nea.z = ea.z * DECAYF + s4.z * OMDF;
    nea.w = ea.w * DECAYF + s4.w * OMDF;
    ((float4*)out_nea)[idx] = nea;
    float cs = cs_sm[k];
    float4 ne;
    ne.x = nea.x / cs; ne.y = nea.y / cs; ne.z = nea.z / cs; ne.w = nea.w / cs;
    ((float4*)out_nemb)[idx] = ne;
}

extern "C" void kernel_launch(void* const* d_in, const int* in_sizes, int n_in,
                              void* d_out, int out_size, void* d_ws, size_t ws_size,
                              hipStream_t stream) {
    const float* z            = (const float*)d_in[0];   // [N, 256]
    const float* emb          = (const float*)d_in[1];   // [1024, 256]
    const float* cluster_size = (const float*)d_in[2];   // [1024]
    const float* embed_avg    = (const float*)d_in[3];   // [1024, 256]

    const int ND = in_sizes[0];       // N*D = 16777216
    const int KD = in_sizes[1];       // K*D = 262144
    const int K  = in_sizes[2];       // 1024
    const int N  = ND / DDIM;         // 65536

    float* out       = (float*)d_out;
    float* out_zq    = out;
    float* out_loss  = out + (size_t)ND;
    float* out_codes = out + (size_t)ND + 1;
    float* out_nemb  = out + (size_t)ND + 1 + N;
    float* out_ncs   = out_nemb + (size_t)KD;
    float* out_nea   = out_ncs + (size_t)K;

    float* ws        = (float*)d_ws;
    float* loss_acc  = ws;                 // [1]
    float* counts    = ws + 1;             // [K]
    float* cs_sm     = counts + K;         // [K]
    float* esq_g     = cs_sm + K;          // [K]
    float* zsq_g     = esq_g + K;          // [N]
    float* embed_sum = zsq_g + N;          // [K*D]

    size_t base_floats = (size_t)1 + 3 * (size_t)K + (size_t)N + (size_t)KD;
    size_t f16_off = (base_floats * sizeof(float) + 255) & ~(size_t)255;
    size_t zbytes  = (size_t)N * 512 * sizeof(f16);      // 64 MB
    size_t ebytes  = (size_t)2 * 262144 * sizeof(f16);   // 1 MB fragment-major
    bool mfma_ok   = ws_size >= f16_off + zbytes + ebytes;

    hipMemsetAsync(loss_acc, 0, sizeof(float), stream);
    if (mfma_ok) {
        f16* zhl  = (f16*)((char*)d_ws + f16_off);
        f16* ehl2 = (f16*)((char*)d_ws + f16_off + zbytes);
        vq_prep<<<(N * 32) / 256, 256, 0, stream>>>(z, zhl, zsq_g);
        vq_prep_e<<<(K * 32) / 256, 256, 0, stream>>>(emb, ehl2, esq_g);
        vq_main_mfma<<<N / BMR, 512, 0, stream>>>(
            zhl, ehl2, esq_g, zsq_g, out_codes);
        vq_epi<<<N / 64, 256, 0, stream>>>(z, emb, out_codes, out_zq, loss_acc);
    } else {
        vq_esq<<<K / 256, 256, 0, stream>>>(emb, esq_g);
        vq_main_f32<<<N / BM, 256, 0, stream>>>(z, emb, esq_g,
                                                out_zq, out_codes, loss_acc);
    }
    vq_scatter<<<K, 256, 0, stream>>>(z, out_codes, embed_sum, counts);
    vq_finalize<<<1, K, 0, stream>>>(cluster_size, counts, loss_acc,
                                     out_ncs, out_loss, cs_sm, 1.0f / (float)ND);
    vq_embed<<<KD / 1024, 256, 0, stream>>>(embed_avg, embed_sum, cs_sm,
                                            out_nea, out_nemb);
}